// Round 18
// baseline (148.297 us; speedup 1.0000x reference)
//
#include <hip/hip_runtime.h>

// ---------------------------------------------------------------------------
// MultiAttention: x[T=1024,N=8,D=1024] -> QKV proj -> 16-head causal attention
// with key padding -> out proj. bf16 MFMA compute, f32 accumulation.
// Round 18: GEMMs get a 3-slot LDS ring (stage t+2, WAITVM(8)) on the proven
// 128x128 schedule -- doubles the latency budget per staged tile (2 compute
// phases instead of 1). Attention/cvt unchanged from R17.
// ---------------------------------------------------------------------------

#define T_SEQ 1024
#define NB 8
#define DMODEL 1024
#define NHEADS 16
#define DK 64

typedef __attribute__((ext_vector_type(8))) short bf16x8;
typedef __attribute__((ext_vector_type(8))) unsigned short u16x8;
typedef __attribute__((ext_vector_type(4))) float f32x4;

#define MFMA16(a, b, c) __builtin_amdgcn_mfma_f32_16x16x32_bf16((a), (b), (c), 0, 0, 0)
#define WAITVM(N) asm volatile("s_waitcnt vmcnt(" #N ")" ::: "memory")

__device__ __forceinline__ unsigned short f2bf(float f) {
  unsigned int u = __float_as_uint(f);
  unsigned int r = (u + 0x7FFFu + ((u >> 16) & 1u)) >> 16;  // RNE
  return (unsigned short)r;
}

__device__ __forceinline__ float fexp2(float x) {  // 2^x, single V_EXP_F32
  float r;
  asm("v_exp_f32 %0, %1" : "=v"(r) : "v"(x));
  return r;
}

__device__ __forceinline__ unsigned cvtpk(float lo, float hi) {  // {bf16(lo),bf16(hi)}
  unsigned r;
  asm("v_cvt_pk_bf16_f32 %0, %1, %2" : "=v"(r) : "v"(lo), "v"(hi));
  return r;
}

__device__ __forceinline__ void gload16(const void* g, void* l) {
  __builtin_amdgcn_global_load_lds((const __attribute__((address_space(1))) void*)g,
                                   (__attribute__((address_space(3))) void*)l, 16, 0, 0);
}

// ---------------- fused f32 -> bf16 conversion + len (block 0) -------------
#define XQ (T_SEQ * NB * DMODEL / 4)
#define WIQ (3 * DMODEL * DMODEL / 4)
#define WOQ (DMODEL * DMODEL / 4)

__global__ __launch_bounds__(256) void cvt_all(const float* __restrict__ x,
                                               const float* __restrict__ w_in,
                                               const float* __restrict__ w_o,
                                               unsigned short* __restrict__ xb,
                                               unsigned short* __restrict__ wib,
                                               unsigned short* __restrict__ wob,
                                               const void* __restrict__ kpm_raw,
                                               int* __restrict__ lens) {
  int i = blockIdx.x * blockDim.x + threadIdx.x;
  if (blockIdx.x == 0 && threadIdx.x < 64) {
    const int* ki = (const int*)kpm_raw;
    const unsigned char* kb = (const unsigned char*)kpm_raw;
    const int lane = threadIdx.x;
    int bad = 0;
    for (int j = lane; j < 2048; j += 64) {
      unsigned v = (unsigned)ki[j];
      bad |= (v != 0u && v != 1u && v != 0x3F800000u) ? 1 : 0;
    }
    for (int m = 1; m < 64; m <<= 1) bad |= __shfl_xor(bad, m);
    for (int n = 0; n < NB; ++n) {
      int cnt = 0;
      if (bad) {
        for (int s = lane; s < T_SEQ; s += 64) cnt += (kb[n * T_SEQ + s] == 0) ? 1 : 0;
      } else {
        for (int s = lane; s < T_SEQ; s += 64) cnt += (ki[n * T_SEQ + s] == 0) ? 1 : 0;
      }
      for (int m = 1; m < 64; m <<= 1) cnt += __shfl_xor(cnt, m);
      if (lane == 0) lens[n] = cnt;
    }
  }
  const float* src;
  unsigned short* dst;
  int j;
  if (i < XQ) {
    src = x; dst = xb; j = i;
  } else if (i < XQ + WIQ) {
    src = w_in; dst = wib; j = i - XQ;
  } else if (i < XQ + WIQ + WOQ) {
    src = w_o; dst = wob; j = i - XQ - WIQ;
  } else {
    return;
  }
  float4 v = reinterpret_cast<const float4*>(src)[j];
  uint2 o;
  o.x = (unsigned)f2bf(v.x) | ((unsigned)f2bf(v.y) << 16);
  o.y = (unsigned)f2bf(v.z) | ((unsigned)f2bf(v.w) << 16);
  reinterpret_cast<uint2*>(dst)[j] = o;
}

#define QSCALE 0.18033688f  // (1/sqrt(64)) * log2(e): softmax uses exp2

// ---------------- 128x128 bf16 GEMM, 3-slot ring staging -------------------
// Ring-3: prologue stages tiles 0,1; iter t stages t+2 into slot (t+2)%3 and
// WAITVM(8) drains only tile t's 4 loads -> each tile's loads get ~2 compute
// phases of latency budget. Slot (t+2)%3 held tile t-1, whose reads finished
// before iter t-1's closing barrier (safe). Staging XOR swizzle as before.
// EPI==0: Q,K scatter to [n,h,t,dk] (Q pre-scaled); V transposed via pad-136
// LDS -> vtb [n,h,dk,t].  EPI==1: f32 C.
template <int EPI>
__global__ __launch_bounds__(256) void gemm_bt_kernel(
    const unsigned short* __restrict__ A, const unsigned short* __restrict__ B,
    const float* __restrict__ bias, float* __restrict__ Cf,
    unsigned short* __restrict__ qb, unsigned short* __restrict__ kb,
    unsigned short* __restrict__ vtb, int M, int N, int K) {
  __shared__ unsigned short lds_all[3 * 8192];  // 3 x [A 4096 | B 4096] u16
  const int tid = threadIdx.x;
  const int brow = blockIdx.x * 128;
  const int bcol = blockIdx.y * 128;
  const int w = tid >> 6, lane = tid & 63;
  const int l15 = lane & 15, lg = lane >> 4;
  const int wr = (w >> 1) * 64, wc = (w & 1) * 64;  // 2x2 wave grid

  f32x4 acc[4][4] = {};
  const int KT = K >> 5;

  auto stage = [&](int t, int buf) {
    const int k0 = t << 5;
    unsigned short* la = lds_all + buf * 8192;
    unsigned short* lb = la + 4096;
#pragma unroll
    for (int i = 0; i < 2; ++i) {
      const int seg = i * 256 + tid;
      const int row = seg >> 2, slot = seg & 3;
      const int qq = (slot ^ ((row >> 1) & 3)) * 8;  // inverse swizzle on src
      gload16(A + (size_t)(brow + row) * K + k0 + qq, la + seg * 8);
      gload16(B + (size_t)(bcol + row) * K + k0 + qq, lb + seg * 8);
    }
  };

  stage(0, 0);
  if (KT > 1) stage(1, 1);
  int sl = 0;
  for (int t = 0; t < KT; ++t) {
    if (t + 2 < KT) {
      stage(t + 2, sl == 0 ? 2 : sl - 1);  // (t+2)%3
      WAITVM(8);                           // drain tile t's 4; leave t+1,t+2
    } else if (t + 1 < KT) {
      WAITVM(4);                           // drain tile t's 4; leave t+1
    } else {
      WAITVM(0);
    }
    __builtin_amdgcn_s_barrier();  // slot sl (tile t) visible to all waves

    const unsigned short* la = lds_all + sl * 8192;
    const unsigned short* lb = la + 4096;
    bf16x8 af[4], bfr[4];
#pragma unroll
    for (int mi = 0; mi < 4; ++mi) {
      const int row = wr + mi * 16 + l15;
      af[mi] = *reinterpret_cast<const bf16x8*>(la + row * 32 +
                                                ((lg ^ ((row >> 1) & 3)) << 3));
    }
#pragma unroll
    for (int ni = 0; ni < 4; ++ni) {
      const int row = wc + ni * 16 + l15;
      bfr[ni] = *reinterpret_cast<const bf16x8*>(lb + row * 32 +
                                                 ((lg ^ ((row >> 1) & 3)) << 3));
    }
#pragma unroll
    for (int mi = 0; mi < 4; ++mi)
#pragma unroll
      for (int ni = 0; ni < 4; ++ni)
        acc[mi][ni] = MFMA16(af[mi], bfr[ni], acc[mi][ni]);
    __builtin_amdgcn_s_barrier();  // reads of slot sl complete
    sl = sl == 2 ? 0 : sl + 1;
  }

  if (EPI == 0 && bcol >= 2 * DMODEL) {
    // ---- V epilogue: transpose via pad-136 LDS, write vtb [n,h,dk,t] ----
    unsigned short* tl = lds_all;
    const int t0 = brow >> 3;  // 16 consecutive t per block
#pragma unroll
    for (int pass = 0; pass < 2; ++pass) {
      if ((w & 1) == pass) {
#pragma unroll
        for (int ni = 0; ni < 4; ++ni) {
          const int c = ni * 16 + l15;
          const float bv = bias[bcol + wc + ni * 16 + l15];
#pragma unroll
          for (int mi = 0; mi < 4; ++mi) {
#pragma unroll
            for (int r = 0; r < 4; ++r) {
              const int row = wr + mi * 16 + lg * 4 + r;  // 0..127
              const int tloc = row >> 3, nn = row & 7;
              tl[c * 136 + nn * 16 + tloc] = f2bf(acc[mi][ni][r] + bv);
            }
          }
        }
      }
      __syncthreads();
      const int hh = ((bcol + pass * 64) - 2 * DMODEL) >> 6;
#pragma unroll
      for (int it = 0; it < 2; ++it) {
        const int task = it * 256 + tid;
        const int c = task >> 3, nn = task & 7;
        const unsigned short* sp = &tl[c * 136 + nn * 16];
        const u16x8 lo = *reinterpret_cast<const u16x8*>(sp);
        const u16x8 hi = *reinterpret_cast<const u16x8*>(sp + 8);
        unsigned short* dst = vtb + (size_t)(nn * NHEADS + hh) * (T_SEQ * DK) +
                              (size_t)c * T_SEQ + t0;
        *reinterpret_cast<u16x8*>(dst) = lo;
        *reinterpret_cast<u16x8*>(dst + 8) = hi;
      }
      __syncthreads();
    }
    return;
  }

#pragma unroll
  for (int mi = 0; mi < 4; ++mi) {
#pragma unroll
    for (int ni = 0; ni < 4; ++ni) {
      const int col = bcol + wc + ni * 16 + l15;
      const float bv = bias[col];
      unsigned short* basep = nullptr;
      if (EPI == 0) basep = col < DMODEL ? qb : kb;
      const float scl = (EPI == 0 && col < DMODEL) ? QSCALE : 1.0f;
      const int c2 = col & (DMODEL - 1);
      const int hh = c2 >> 6, dk = c2 & 63;
#pragma unroll
      for (int r = 0; r < 4; ++r) {
        const int row = brow + wr + mi * 16 + lg * 4 + r;
        const float v = (acc[mi][ni][r] + bv) * scl;
        if (EPI == 1) {
          Cf[(size_t)row * N + col] = v;
        } else {
          const int t = row >> 3, n = row & 7;  // row = t*NB + n
          basep[(size_t)(n * NHEADS + hh) * (T_SEQ * DK) + t * DK + dk] = f2bf(v);
        }
      }
    }
  }
}

// ---------------- fused causal attention, paired-q-stream K/V pass ---------
#define PLD 72

__device__ __forceinline__ void stage_kv(const unsigned short* kp_base,
                                         const unsigned short* vp_base, int s0,
                                         unsigned short* kl, unsigned short* vl, int tid) {
#pragma unroll
  for (int i = 0; i < 2; ++i) {
    const int seg = i * 256 + tid;
    const int r = seg >> 3, c8 = seg & 7;
    const int xc = (c8 ^ (r & 7)) * 8;
    gload16(kp_base + (((size_t)(s0 + r)) << 6) + xc, kl + seg * 8);
    gload16(vp_base + (size_t)r * T_SEQ + s0 + xc, vl + seg * 8);
  }
}

__global__ __launch_bounds__(256, 3) void attn_kernel(
    const unsigned short* __restrict__ qb, const unsigned short* __restrict__ kb,
    const unsigned short* __restrict__ vtb, const int* __restrict__ lens,
    unsigned short* __restrict__ attn_out) {
  __shared__ unsigned short k_lds[2][64 * 64];
  __shared__ unsigned short v_lds[2][64 * 64];
  __shared__ unsigned short p_lds[4 * 16 * PLD];
  const int bid = blockIdx.x;
  const int x = bid & 7;
  const int rem = bid >> 3;
  const int nh = (rem & 15) * 8 + x;
  const int pr = rem >> 4;
  const int n = nh >> 4;
  const int h = nh & 15;
  const int tid = threadIdx.x;
  const int w = tid >> 6, lane = tid & 63;
  const int l15 = lane & 15, lg = lane >> 4;
  const int len_n = lens[n];
  const int ltiles = (len_n + 63) >> 6;

  const unsigned short* kp_base = kb + (size_t)nh * (T_SEQ * DK);
  const unsigned short* vp_base = vtb + (size_t)nh * (T_SEQ * DK);
  const unsigned short* q_base = qb + (size_t)nh * (T_SEQ * DK);
  unsigned short* pw = p_lds + w * 16 * PLD;

  bf16x8 ones;
#pragma unroll
  for (int j = 0; j < 8; ++j) ones[j] = (short)0x3F80;

  const int qtA = pr, qtB = 15 - pr;
  int nA = qtA + 1, nB = qtB + 1;
  if (ltiles < nA) nA = ltiles;
  if (ltiles < nB) nB = ltiles;

  const unsigned short* qpA = q_base + (size_t)(qtA * 64 + w * 16 + l15) * DK;
  const unsigned short* qpB = q_base + (size_t)(qtB * 64 + w * 16 + l15) * DK;
  const bf16x8 qaA0 = *reinterpret_cast<const bf16x8*>(qpA + lg * 8);
  const bf16x8 qaA1 = *reinterpret_cast<const bf16x8*>(qpA + 32 + lg * 8);
  const bf16x8 qaB0 = *reinterpret_cast<const bf16x8*>(qpB + lg * 8);
  const bf16x8 qaB1 = *reinterpret_cast<const bf16x8*>(qpB + 32 + lg * 8);

  f32x4 oA[4] = {}, oB[4] = {};
  float lA[4] = {}, lB[4] = {};

  const int tbA = qtA * 64 + w * 16 + lg * 4;
  const int tbB = qtB * 64 + w * 16 + lg * 4;
  const int tlaneA = qtA * 64 + w * 16 + l15;
  const int tlaneB = qtB * 64 + w * 16 + l15;

  int cur = 0;
  stage_kv(kp_base, vp_base, 0, k_lds[0], v_lds[0], tid);

  for (int tile = 0; tile < nB; ++tile) {
    const int s0 = tile * 64;
    if (tile + 1 < nB) {
      stage_kv(kp_base, vp_base, s0 + 64, k_lds[cur ^ 1], v_lds[cur ^ 1], tid);
      WAITVM(4);
    } else {
      WAITVM(0);
    }
    __builtin_amdgcn_s_barrier();

    const bool actA = tile < nA;

    f32x4 sA[4] = {}, sB[4] = {};
    __builtin_amdgcn_s_setprio(1);
#pragma unroll
    for (int ct = 0; ct < 4; ++ct) {
      const int rl = ct * 16 + l15;
      const int c0 = lg ^ (rl & 7);
      const bf16x8 kf0 = *reinterpret_cast<const bf16x8*>(&k_lds[cur][rl * 64 + c0 * 8]);
      const bf16x8 kf1 = *reinterpret_cast<const bf16x8*>(&k_lds[cur][rl * 64 + (c0 ^ 4) * 8]);
      if (actA) {
        sA[ct] = MFMA16(kf0, qaA0, sA[ct]);
        sA[ct] = MFMA16(kf1, qaA1, sA[ct]);
      }
      sB[ct] = MFMA16(kf0, qaB0, sB[ct]);
      sB[ct] = MFMA16(kf1, qaB1, sB[ct]);
    }
    __builtin_amdgcn_s_setprio(0);
    bf16x8 vf[4][2];
#pragma unroll
    for (int ct = 0; ct < 4; ++ct) {
      const int rl = ct * 16 + l15;
      const int c0 = lg ^ (rl & 7);
      vf[ct][0] = *reinterpret_cast<const bf16x8*>(&v_lds[cur][rl * 64 + c0 * 8]);
      vf[ct][1] = *reinterpret_cast<const bf16x8*>(&v_lds[cur][rl * 64 + (c0 ^ 4) * 8]);
    }
    const int boundary = ((tile + 1) << 6) > len_n;

    if (actA) {
      if ((tile == qtA) | boundary) {
#pragma unroll
        for (int ct = 0; ct < 4; ++ct) {
          const int sb = s0 + ct * 16 + lg * 4;
#pragma unroll
          for (int r = 0; r < 4; ++r)
            if (sb + r > tlaneA || sb + r >= len_n) sA[ct][r] = -1e30f;
        }
      }
#pragma unroll
      for (int ct = 0; ct < 4; ++ct) {
        uint2 pk;
        pk.x = cvtpk(fexp2(sA[ct][0]), fexp2(sA[ct][1]));
        pk.y = cvtpk(fexp2(sA[ct][2]), fexp2(sA[ct][3]));
        *reinterpret_cast<uint2*>(pw + l15 * PLD + ct * 16 + lg * 4) = pk;
      }
      const bf16x8 pa0 = *reinterpret_cast<const bf16x8*>(pw + l15 * PLD + lg * 8);
      const bf16x8 pa1 = *reinterpret_cast<const bf16x8*>(pw + l15 * PLD + 32 + lg * 8);
      f32x4 lacc = {};
      __builtin_amdgcn_s_setprio(1);
      lacc = MFMA16(pa0, ones, lacc);
      lacc = MFMA16(pa1, ones, lacc);
#pragma unroll
      for (int ct = 0; ct < 4; ++ct) {
        oA[ct] = MFMA16(pa0, vf[ct][0], oA[ct]);
        oA[ct] = MFMA16(pa1, vf[ct][1], oA[ct]);
      }
      __builtin_amdgcn_s_setprio(0);
#pragma unroll
      for (int r = 0; r < 4; ++r) lA[r] += lacc[r];
    }

    {
      if ((tile == qtB) | boundary) {
#pragma unroll
        for (int ct = 0; ct < 4; ++ct) {
          const int sb = s0 + ct * 16 + lg * 4;
#pragma unroll
          for (int r = 0; r < 4; ++r)
            if (sb + r > tlaneB || sb + r >= len_n) sB[ct][r] = -1e30f;
        }
      }
#pragma unroll
      for (int ct = 0; ct < 4; ++ct) {
        uint2 pk;
        pk.x = cvtpk(fexp2(sB[ct][0]), fexp2(sB[ct][1]));
        pk.y = cvtpk(fexp2(sB[ct][2]), fexp2(sB[ct][3]));
        *reinterpret_cast<uint2*>(pw + l15 * PLD + ct * 16 + lg * 4) = pk;
      }
      const bf16x8 pa0 = *reinterpret_cast<const bf16x8*>(pw + l15 * PLD + lg * 8);
      const bf16x8 pa1 = *reinterpret_cast<const bf16x8*>(pw + l15 * PLD + 32 + lg * 8);
      f32x4 lacc = {};
      __builtin_amdgcn_s_setprio(1);
      lacc = MFMA16(pa0, ones, lacc);
      lacc = MFMA16(pa1, ones, lacc);
#pragma unroll
      for (int ct = 0; ct < 4; ++ct) {
        oB[ct] = MFMA16(pa0, vf[ct][0], oB[ct]);
        oB[ct] = MFMA16(pa1, vf[ct][1], oB[ct]);
      }
      __builtin_amdgcn_s_setprio(0);
#pragma unroll
      for (int r = 0; r < 4; ++r) lB[r] += lacc[r];
    }

    __builtin_amdgcn_s_barrier();
    cur ^= 1;
  }

#pragma unroll
  for (int r = 0; r < 4; ++r) { lA[r] = 1.0f / lA[r]; lB[r] = 1.0f / lB[r]; }
#pragma unroll
  for (int ct = 0; ct < 4; ++ct) {
    const int d = h * DK + ct * 16 + l15;
#pragma unroll
    for (int r = 0; r < 4; ++r) {
      attn_out[((size_t)(tbA + r) * NB + n) * DMODEL + d] = f2bf(oA[ct][r] * lA[r]);
      attn_out[((size_t)(tbB + r) * NB + n) * DMODEL + d] = f2bf(oB[ct][r] * lB[r]);
    }
  }
}

// ---------------------------------------------------------------------------
extern "C" void kernel_launch(void* const* d_in, const int* in_sizes, int n_in,
                              void* d_out, int out_size, void* d_ws, size_t ws_size,
                              hipStream_t stream) {
  const float* x = (const float*)d_in[0];
  const float* w_in = (const float*)d_in[1];
  const float* b_in = (const float*)d_in[2];
  const float* w_o = (const float*)d_in[3];
  const float* b_o = (const float*)d_in[4];
  const void* kpm = (const void*)d_in[6];
  float* out = (float*)d_out;

  char* ws = (char*)d_ws;
  unsigned short* x_bf = (unsigned short*)(ws + 0);           // 16.78 MB
  unsigned short* win_bf = (unsigned short*)(ws + 16777216);  // 6.29 MB
  unsigned short* wo_bf = (unsigned short*)(ws + 23068672);   // 2.10 MB
  unsigned short* qb = (unsigned short*)(ws + 25165824);      // 16.78 MB
  unsigned short* kb = (unsigned short*)(ws + 41943040);      // 16.78 MB
  unsigned short* vtb = (unsigned short*)(ws + 58720256);     // 16.78 MB [n,h,dk,t]
  unsigned short* attn_bf = (unsigned short*)(ws + 0);        // alias x_bf
  int* lens = (int*)(ws + 92274688);                          // 32 B

  cvt_all<<<(XQ + WIQ + WOQ + 255) / 256, 256, 0, stream>>>(x, w_in, w_o, x_bf, win_bf, wo_bf,
                                                            kpm, lens);
  // QKV projection: Q pre-scaled; V transposed in-epilogue -> vtb
  gemm_bt_kernel<0><<<dim3(64, 24), 256, 0, stream>>>(x_bf, win_bf, b_in, nullptr, qb, kb, vtb,
                                                      T_SEQ * NB, 3 * DMODEL, DMODEL);
  // fused attention (paired q-streams, swapped QK^T, exp2 no-max softmax)
  attn_kernel<<<NB * NHEADS * 8, 256, 0, stream>>>(qb, kb, vtb, lens, attn_bf);
  // output projection: [8192,1024] x [1024,1024]^T -> f32 out
  gemm_bt_kernel<1><<<dim3(64, 8), 256, 0, stream>>>(attn_bf, wo_bf, b_o, out, nullptr, nullptr,
                                                     nullptr, T_SEQ * NB, DMODEL, DMODEL);
}

// Round 19
// 142.240 us; speedup vs baseline: 1.0426x; 1.0426x over previous
//
#include <hip/hip_runtime.h>

// ---------------------------------------------------------------------------
// MultiAttention: x[T=1024,N=8,D=1024] -> QKV proj -> 16-head causal attention
// with key padding -> out proj. bf16 MFMA compute, f32 accumulation.
// Round 19 (FINAL): best-measured configuration (= R17, 142.4 us):
//   cvt_all (x+weights -> bf16, + mask-width-detecting len compute)
//   gemm_qkv_wide: 256x128 blocks, 128x64 wave tiles, dbuf counted-vmcnt;
//     Q pre-scaled by 0.125*log2e; V transposed in-epilogue -> [n,h,dk,t]
//   attn_kernel: paired q-streams (qt, 15-qt) in one K/V LDS pipeline,
//     XCD-local heads, swapped QK^T, exp2 no-max softmax, rowsum via MFMA
//   gemm_out_kernel: 128x128 dbuf counted-vmcnt, f32 out
// Journal: six GEMM1 schedules converge at ~700 TF for this short-K shape;
// attn 555 TF; cvt at HBM ceiling. 400 us (R3 naive) -> 142 us.
// ---------------------------------------------------------------------------

#define T_SEQ 1024
#define NB 8
#define DMODEL 1024
#define NHEADS 16
#define DK 64

typedef __attribute__((ext_vector_type(8))) short bf16x8;
typedef __attribute__((ext_vector_type(8))) unsigned short u16x8;
typedef __attribute__((ext_vector_type(4))) float f32x4;

#define MFMA16(a, b, c) __builtin_amdgcn_mfma_f32_16x16x32_bf16((a), (b), (c), 0, 0, 0)
#define WAITVM(N) asm volatile("s_waitcnt vmcnt(" #N ")" ::: "memory")

__device__ __forceinline__ unsigned short f2bf(float f) {
  unsigned int u = __float_as_uint(f);
  unsigned int r = (u + 0x7FFFu + ((u >> 16) & 1u)) >> 16;  // RNE
  return (unsigned short)r;
}

__device__ __forceinline__ float fexp2(float x) {  // 2^x, single V_EXP_F32
  float r;
  asm("v_exp_f32 %0, %1" : "=v"(r) : "v"(x));
  return r;
}

__device__ __forceinline__ unsigned cvtpk(float lo, float hi) {  // {bf16(lo),bf16(hi)}
  unsigned r;
  asm("v_cvt_pk_bf16_f32 %0, %1, %2" : "=v"(r) : "v"(lo), "v"(hi));
  return r;
}

__device__ __forceinline__ void gload16(const void* g, void* l) {
  __builtin_amdgcn_global_load_lds((const __attribute__((address_space(1))) void*)g,
                                   (__attribute__((address_space(3))) void*)l, 16, 0, 0);
}

// ---------------- fused f32 -> bf16 conversion + len (block 0) -------------
#define XQ (T_SEQ * NB * DMODEL / 4)
#define WIQ (3 * DMODEL * DMODEL / 4)
#define WOQ (DMODEL * DMODEL / 4)

__global__ __launch_bounds__(256) void cvt_all(const float* __restrict__ x,
                                               const float* __restrict__ w_in,
                                               const float* __restrict__ w_o,
                                               unsigned short* __restrict__ xb,
                                               unsigned short* __restrict__ wib,
                                               unsigned short* __restrict__ wob,
                                               const void* __restrict__ kpm_raw,
                                               int* __restrict__ lens) {
  int i = blockIdx.x * blockDim.x + threadIdx.x;
  if (blockIdx.x == 0 && threadIdx.x < 64) {
    const int* ki = (const int*)kpm_raw;
    const unsigned char* kb = (const unsigned char*)kpm_raw;
    const int lane = threadIdx.x;
    int bad = 0;
    for (int j = lane; j < 2048; j += 64) {
      unsigned v = (unsigned)ki[j];
      bad |= (v != 0u && v != 1u && v != 0x3F800000u) ? 1 : 0;
    }
    for (int m = 1; m < 64; m <<= 1) bad |= __shfl_xor(bad, m);
    for (int n = 0; n < NB; ++n) {
      int cnt = 0;
      if (bad) {
        for (int s = lane; s < T_SEQ; s += 64) cnt += (kb[n * T_SEQ + s] == 0) ? 1 : 0;
      } else {
        for (int s = lane; s < T_SEQ; s += 64) cnt += (ki[n * T_SEQ + s] == 0) ? 1 : 0;
      }
      for (int m = 1; m < 64; m <<= 1) cnt += __shfl_xor(cnt, m);
      if (lane == 0) lens[n] = cnt;
    }
  }
  const float* src;
  unsigned short* dst;
  int j;
  if (i < XQ) {
    src = x; dst = xb; j = i;
  } else if (i < XQ + WIQ) {
    src = w_in; dst = wib; j = i - XQ;
  } else if (i < XQ + WIQ + WOQ) {
    src = w_o; dst = wob; j = i - XQ - WIQ;
  } else {
    return;
  }
  float4 v = reinterpret_cast<const float4*>(src)[j];
  uint2 o;
  o.x = (unsigned)f2bf(v.x) | ((unsigned)f2bf(v.y) << 16);
  o.y = (unsigned)f2bf(v.z) | ((unsigned)f2bf(v.w) << 16);
  reinterpret_cast<uint2*>(dst)[j] = o;
}

#define QSCALE 0.18033688f  // (1/sqrt(64)) * log2(e): softmax uses exp2

// ---------------- GEMM1: 256x128-block QKV projection ----------------------
// 4 waves (2x2), wave tile 128x64. Double-buffered staging + counted WAITVM(6).
// Q,K scatter to [n,h,t,dk] (Q pre-scaled); V transposed via pad-276 LDS.
__global__ __launch_bounds__(256, 2) void gemm_qkv_wide(
    const unsigned short* __restrict__ A, const unsigned short* __restrict__ B,
    const float* __restrict__ bias, unsigned short* __restrict__ qb,
    unsigned short* __restrict__ kb, unsigned short* __restrict__ vtb) {
  constexpr int K = DMODEL;
  __shared__ unsigned short lds_all[2 * 12288];  // [2][A 8192 | B 4096]
  const int tid = threadIdx.x;
  const int brow = blockIdx.x * 256;
  const int bcol = blockIdx.y * 128;
  const int w = tid >> 6, lane = tid & 63;
  const int l15 = lane & 15, lg = lane >> 4;
  const int wm = w >> 1, wn = w & 1;  // 2x2 wave grid: 128-row x 64-col tiles

  f32x4 acc[8][4] = {};
  const int KT = K >> 5;  // 32

  auto stage = [&](int t, int buf) {
    const int k0 = t << 5;
    unsigned short* la = lds_all + buf * 12288;
    unsigned short* lb = la + 8192;
#pragma unroll
    for (int i = 0; i < 4; ++i) {  // A: 1024 chunks of 16B (256 rows x 32 k)
      const int seg = i * 256 + tid;
      const int row = seg >> 2, slot = seg & 3;
      const int qq = (slot ^ ((row >> 1) & 3)) * 8;  // inverse swizzle on src
      gload16(A + (size_t)(brow + row) * K + k0 + qq, la + seg * 8);
    }
#pragma unroll
    for (int i = 0; i < 2; ++i) {  // B: 512 chunks (128 rows x 32 k)
      const int seg = i * 256 + tid;
      const int row = seg >> 2, slot = seg & 3;
      const int qq = (slot ^ ((row >> 1) & 3)) * 8;
      gload16(B + (size_t)(bcol + row) * K + k0 + qq, lb + seg * 8);
    }
  };

  stage(0, 0);
  for (int t = 0; t < KT; ++t) {
    const int cur = t & 1;
    if (t + 1 < KT) {
      stage(t + 1, cur ^ 1);
      WAITVM(6);  // drain tile t's 6 loads; tile t+1's stay in flight
    } else {
      WAITVM(0);
    }
    __builtin_amdgcn_s_barrier();

    const unsigned short* la = lds_all + cur * 12288;
    const unsigned short* lb = la + 8192;
    bf16x8 bfr[4];
#pragma unroll
    for (int ni = 0; ni < 4; ++ni) {
      const int row = wn * 64 + ni * 16 + l15;
      bfr[ni] = *reinterpret_cast<const bf16x8*>(lb + row * 32 +
                                                 ((lg ^ ((row >> 1) & 3)) << 3));
    }
#pragma unroll
    for (int mi = 0; mi < 8; ++mi) {
      const int row = wm * 128 + mi * 16 + l15;
      const bf16x8 af = *reinterpret_cast<const bf16x8*>(la + row * 32 +
                                                         ((lg ^ ((row >> 1) & 3)) << 3));
#pragma unroll
      for (int ni = 0; ni < 4; ++ni) acc[mi][ni] = MFMA16(af, bfr[ni], acc[mi][ni]);
    }
    __builtin_amdgcn_s_barrier();
  }

  if (bcol >= 2 * DMODEL) {
    // ---- V epilogue: transpose via pad-276 LDS, write vtb [n,h,dk,t] ----
    unsigned short* tl = lds_all;  // 64 x 276 u16 = 17664
    const int t0 = brow >> 3;      // 32 consecutive t per block
#pragma unroll
    for (int pass = 0; pass < 2; ++pass) {
      if (wn == pass) {  // waves owning cols pass*64..+63
#pragma unroll
        for (int ni = 0; ni < 4; ++ni) {
          const int c = ni * 16 + l15;  // 0..63 within half
          const float bv = bias[bcol + pass * 64 + c];
#pragma unroll
          for (int mi = 0; mi < 8; ++mi) {
#pragma unroll
            for (int r = 0; r < 4; ++r) {
              const int row = wm * 128 + mi * 16 + lg * 4 + r;  // 0..255
              const int tloc = row >> 3, nn = row & 7;
              tl[c * 276 + nn * 32 + tloc] = f2bf(acc[mi][ni][r] + bv);
            }
          }
        }
      }
      __syncthreads();
      const int hh = ((bcol + pass * 64) - 2 * DMODEL) >> 6;
#pragma unroll
      for (int it = 0; it < 2; ++it) {
        const int task = it * 256 + tid;  // 512 tasks: (c, nn), 64B each
        const int c = task >> 3, nn = task & 7;
        const unsigned short* sp = &tl[c * 276 + nn * 32];
        unsigned short* dst = vtb + (size_t)(nn * NHEADS + hh) * (T_SEQ * DK) +
                              (size_t)c * T_SEQ + t0;
#pragma unroll
        for (int q = 0; q < 4; ++q)
          *reinterpret_cast<u16x8*>(dst + q * 8) = *reinterpret_cast<const u16x8*>(sp + q * 8);
      }
      __syncthreads();
    }
    return;
  }

  // ---- Q/K scatter epilogue ----
#pragma unroll
  for (int ni = 0; ni < 4; ++ni) {
    const int col = bcol + wn * 64 + ni * 16 + l15;
    const float bv = bias[col];
    unsigned short* basep = col < DMODEL ? qb : kb;
    const float scl = col < DMODEL ? QSCALE : 1.0f;
    const int c2 = col & (DMODEL - 1);
    const int hh = c2 >> 6, dk = c2 & 63;
#pragma unroll
    for (int mi = 0; mi < 8; ++mi) {
#pragma unroll
      for (int r = 0; r < 4; ++r) {
        const int row = brow + wm * 128 + mi * 16 + lg * 4 + r;
        const float v = (acc[mi][ni][r] + bv) * scl;
        const int t = row >> 3, n = row & 7;  // row = t*NB + n
        basep[(size_t)(n * NHEADS + hh) * (T_SEQ * DK) + t * DK + dk] = f2bf(v);
      }
    }
  }
}

// ---------------- GEMM2: 128x128 dbuf kernel, f32 out ----------------------
__global__ __launch_bounds__(256) void gemm_out_kernel(
    const unsigned short* __restrict__ A, const unsigned short* __restrict__ B,
    const float* __restrict__ bias, float* __restrict__ Cf, int M, int N, int K) {
  __shared__ unsigned short lds_all[2 * 8192];
  const int tid = threadIdx.x;
  const int brow = blockIdx.x * 128;
  const int bcol = blockIdx.y * 128;
  const int w = tid >> 6, lane = tid & 63;
  const int l15 = lane & 15, lg = lane >> 4;
  const int wr = (w >> 1) * 64, wc = (w & 1) * 64;

  f32x4 acc[4][4] = {};
  const int KT = K >> 5;

  auto stage = [&](int t, int buf) {
    const int k0 = t << 5;
    unsigned short* la = lds_all + buf * 8192;
    unsigned short* lb = la + 4096;
#pragma unroll
    for (int i = 0; i < 2; ++i) {
      const int seg = i * 256 + tid;
      const int row = seg >> 2, slot = seg & 3;
      const int qq = (slot ^ ((row >> 1) & 3)) * 8;
      gload16(A + (size_t)(brow + row) * K + k0 + qq, la + seg * 8);
      gload16(B + (size_t)(bcol + row) * K + k0 + qq, lb + seg * 8);
    }
  };

  stage(0, 0);
  for (int t = 0; t < KT; ++t) {
    const int cur = t & 1;
    if (t + 1 < KT) {
      stage(t + 1, cur ^ 1);
      WAITVM(4);
    } else {
      WAITVM(0);
    }
    __builtin_amdgcn_s_barrier();

    const unsigned short* la = lds_all + cur * 8192;
    const unsigned short* lb = la + 4096;
    bf16x8 af[4], bfr[4];
#pragma unroll
    for (int mi = 0; mi < 4; ++mi) {
      const int row = wr + mi * 16 + l15;
      af[mi] = *reinterpret_cast<const bf16x8*>(la + row * 32 +
                                                ((lg ^ ((row >> 1) & 3)) << 3));
    }
#pragma unroll
    for (int ni = 0; ni < 4; ++ni) {
      const int row = wc + ni * 16 + l15;
      bfr[ni] = *reinterpret_cast<const bf16x8*>(lb + row * 32 +
                                                 ((lg ^ ((row >> 1) & 3)) << 3));
    }
#pragma unroll
    for (int mi = 0; mi < 4; ++mi)
#pragma unroll
      for (int ni = 0; ni < 4; ++ni)
        acc[mi][ni] = MFMA16(af[mi], bfr[ni], acc[mi][ni]);
    __builtin_amdgcn_s_barrier();
  }

#pragma unroll
  for (int mi = 0; mi < 4; ++mi) {
#pragma unroll
    for (int ni = 0; ni < 4; ++ni) {
      const int col = bcol + wc + ni * 16 + l15;
      const float bv = bias[col];
#pragma unroll
      for (int r = 0; r < 4; ++r) {
        const int row = brow + wr + mi * 16 + lg * 4 + r;
        Cf[(size_t)row * N + col] = acc[mi][ni][r] + bv;
      }
    }
  }
}

// ---------------- fused causal attention, paired-q-stream K/V pass ---------
#define PLD 72

__device__ __forceinline__ void stage_kv(const unsigned short* kp_base,
                                         const unsigned short* vp_base, int s0,
                                         unsigned short* kl, unsigned short* vl, int tid) {
#pragma unroll
  for (int i = 0; i < 2; ++i) {
    const int seg = i * 256 + tid;
    const int r = seg >> 3, c8 = seg & 7;
    const int xc = (c8 ^ (r & 7)) * 8;
    gload16(kp_base + (((size_t)(s0 + r)) << 6) + xc, kl + seg * 8);
    gload16(vp_base + (size_t)r * T_SEQ + s0 + xc, vl + seg * 8);
  }
}

__global__ __launch_bounds__(256, 3) void attn_kernel(
    const unsigned short* __restrict__ qb, const unsigned short* __restrict__ kb,
    const unsigned short* __restrict__ vtb, const int* __restrict__ lens,
    unsigned short* __restrict__ attn_out) {
  __shared__ unsigned short k_lds[2][64 * 64];
  __shared__ unsigned short v_lds[2][64 * 64];
  __shared__ unsigned short p_lds[4 * 16 * PLD];
  const int bid = blockIdx.x;
  const int x = bid & 7;
  const int rem = bid >> 3;
  const int nh = (rem & 15) * 8 + x;
  const int pr = rem >> 4;
  const int n = nh >> 4;
  const int h = nh & 15;
  const int tid = threadIdx.x;
  const int w = tid >> 6, lane = tid & 63;
  const int l15 = lane & 15, lg = lane >> 4;
  const int len_n = lens[n];
  const int ltiles = (len_n + 63) >> 6;

  const unsigned short* kp_base = kb + (size_t)nh * (T_SEQ * DK);
  const unsigned short* vp_base = vtb + (size_t)nh * (T_SEQ * DK);
  const unsigned short* q_base = qb + (size_t)nh * (T_SEQ * DK);
  unsigned short* pw = p_lds + w * 16 * PLD;

  bf16x8 ones;
#pragma unroll
  for (int j = 0; j < 8; ++j) ones[j] = (short)0x3F80;

  const int qtA = pr, qtB = 15 - pr;
  int nA = qtA + 1, nB = qtB + 1;
  if (ltiles < nA) nA = ltiles;
  if (ltiles < nB) nB = ltiles;

  const unsigned short* qpA = q_base + (size_t)(qtA * 64 + w * 16 + l15) * DK;
  const unsigned short* qpB = q_base + (size_t)(qtB * 64 + w * 16 + l15) * DK;
  const bf16x8 qaA0 = *reinterpret_cast<const bf16x8*>(qpA + lg * 8);
  const bf16x8 qaA1 = *reinterpret_cast<const bf16x8*>(qpA + 32 + lg * 8);
  const bf16x8 qaB0 = *reinterpret_cast<const bf16x8*>(qpB + lg * 8);
  const bf16x8 qaB1 = *reinterpret_cast<const bf16x8*>(qpB + 32 + lg * 8);

  f32x4 oA[4] = {}, oB[4] = {};
  float lA[4] = {}, lB[4] = {};

  const int tbA = qtA * 64 + w * 16 + lg * 4;
  const int tbB = qtB * 64 + w * 16 + lg * 4;
  const int tlaneA = qtA * 64 + w * 16 + l15;
  const int tlaneB = qtB * 64 + w * 16 + l15;

  int cur = 0;
  stage_kv(kp_base, vp_base, 0, k_lds[0], v_lds[0], tid);

  for (int tile = 0; tile < nB; ++tile) {
    const int s0 = tile * 64;
    if (tile + 1 < nB) {
      stage_kv(kp_base, vp_base, s0 + 64, k_lds[cur ^ 1], v_lds[cur ^ 1], tid);
      WAITVM(4);
    } else {
      WAITVM(0);
    }
    __builtin_amdgcn_s_barrier();

    const bool actA = tile < nA;

    f32x4 sA[4] = {}, sB[4] = {};
    __builtin_amdgcn_s_setprio(1);
#pragma unroll
    for (int ct = 0; ct < 4; ++ct) {
      const int rl = ct * 16 + l15;
      const int c0 = lg ^ (rl & 7);
      const bf16x8 kf0 = *reinterpret_cast<const bf16x8*>(&k_lds[cur][rl * 64 + c0 * 8]);
      const bf16x8 kf1 = *reinterpret_cast<const bf16x8*>(&k_lds[cur][rl * 64 + (c0 ^ 4) * 8]);
      if (actA) {
        sA[ct] = MFMA16(kf0, qaA0, sA[ct]);
        sA[ct] = MFMA16(kf1, qaA1, sA[ct]);
      }
      sB[ct] = MFMA16(kf0, qaB0, sB[ct]);
      sB[ct] = MFMA16(kf1, qaB1, sB[ct]);
    }
    __builtin_amdgcn_s_setprio(0);
    bf16x8 vf[4][2];
#pragma unroll
    for (int ct = 0; ct < 4; ++ct) {
      const int rl = ct * 16 + l15;
      const int c0 = lg ^ (rl & 7);
      vf[ct][0] = *reinterpret_cast<const bf16x8*>(&v_lds[cur][rl * 64 + c0 * 8]);
      vf[ct][1] = *reinterpret_cast<const bf16x8*>(&v_lds[cur][rl * 64 + (c0 ^ 4) * 8]);
    }
    const int boundary = ((tile + 1) << 6) > len_n;

    if (actA) {
      if ((tile == qtA) | boundary) {
#pragma unroll
        for (int ct = 0; ct < 4; ++ct) {
          const int sb = s0 + ct * 16 + lg * 4;
#pragma unroll
          for (int r = 0; r < 4; ++r)
            if (sb + r > tlaneA || sb + r >= len_n) sA[ct][r] = -1e30f;
        }
      }
#pragma unroll
      for (int ct = 0; ct < 4; ++ct) {
        uint2 pk;
        pk.x = cvtpk(fexp2(sA[ct][0]), fexp2(sA[ct][1]));
        pk.y = cvtpk(fexp2(sA[ct][2]), fexp2(sA[ct][3]));
        *reinterpret_cast<uint2*>(pw + l15 * PLD + ct * 16 + lg * 4) = pk;
      }
      const bf16x8 pa0 = *reinterpret_cast<const bf16x8*>(pw + l15 * PLD + lg * 8);
      const bf16x8 pa1 = *reinterpret_cast<const bf16x8*>(pw + l15 * PLD + 32 + lg * 8);
      f32x4 lacc = {};
      __builtin_amdgcn_s_setprio(1);
      lacc = MFMA16(pa0, ones, lacc);
      lacc = MFMA16(pa1, ones, lacc);
#pragma unroll
      for (int ct = 0; ct < 4; ++ct) {
        oA[ct] = MFMA16(pa0, vf[ct][0], oA[ct]);
        oA[ct] = MFMA16(pa1, vf[ct][1], oA[ct]);
      }
      __builtin_amdgcn_s_setprio(0);
#pragma unroll
      for (int r = 0; r < 4; ++r) lA[r] += lacc[r];
    }

    {
      if ((tile == qtB) | boundary) {
#pragma unroll
        for (int ct = 0; ct < 4; ++ct) {
          const int sb = s0 + ct * 16 + lg * 4;
#pragma unroll
          for (int r = 0; r < 4; ++r)
            if (sb + r > tlaneB || sb + r >= len_n) sB[ct][r] = -1e30f;
        }
      }
#pragma unroll
      for (int ct = 0; ct < 4; ++ct) {
        uint2 pk;
        pk.x = cvtpk(fexp2(sB[ct][0]), fexp2(sB[ct][1]));
        pk.y = cvtpk(fexp2(sB[ct][2]), fexp2(sB[ct][3]));
        *reinterpret_cast<uint2*>(pw + l15 * PLD + ct * 16 + lg * 4) = pk;
      }
      const bf16x8 pa0 = *reinterpret_cast<const bf16x8*>(pw + l15 * PLD + lg * 8);
      const bf16x8 pa1 = *reinterpret_cast<const bf16x8*>(pw + l15 * PLD + 32 + lg * 8);
      f32x4 lacc = {};
      __builtin_amdgcn_s_setprio(1);
      lacc = MFMA16(pa0, ones, lacc);
      lacc = MFMA16(pa1, ones, lacc);
#pragma unroll
      for (int ct = 0; ct < 4; ++ct) {
        oB[ct] = MFMA16(pa0, vf[ct][0], oB[ct]);
        oB[ct] = MFMA16(pa1, vf[ct][1], oB[ct]);
      }
      __builtin_amdgcn_s_setprio(0);
#pragma unroll
      for (int r = 0; r < 4; ++r) lB[r] += lacc[r];
    }

    __builtin_amdgcn_s_barrier();
    cur ^= 1;
  }

#pragma unroll
  for (int r = 0; r < 4; ++r) { lA[r] = 1.0f / lA[r]; lB[r] = 1.0f / lB[r]; }
#pragma unroll
  for (int ct = 0; ct < 4; ++ct) {
    const int d = h * DK + ct * 16 + l15;
#pragma unroll
    for (int r = 0; r < 4; ++r) {
      attn_out[((size_t)(tbA + r) * NB + n) * DMODEL + d] = f2bf(oA[ct][r] * lA[r]);
      attn_out[((size_t)(tbB + r) * NB + n) * DMODEL + d] = f2bf(oB[ct][r] * lB[r]);
    }
  }
}

// ---------------------------------------------------------------------------
extern "C" void kernel_launch(void* const* d_in, const int* in_sizes, int n_in,
                              void* d_out, int out_size, void* d_ws, size_t ws_size,
                              hipStream_t stream) {
  const float* x = (const float*)d_in[0];
  const float* w_in = (const float*)d_in[1];
  const float* b_in = (const float*)d_in[2];
  const float* w_o = (const float*)d_in[3];
  const float* b_o = (const float*)d_in[4];
  const void* kpm = (const void*)d_in[6];
  float* out = (float*)d_out;

  char* ws = (char*)d_ws;
  unsigned short* x_bf = (unsigned short*)(ws + 0);           // 16.78 MB
  unsigned short* win_bf = (unsigned short*)(ws + 16777216);  // 6.29 MB
  unsigned short* wo_bf = (unsigned short*)(ws + 23068672);   // 2.10 MB
  unsigned short* qb = (unsigned short*)(ws + 25165824);      // 16.78 MB
  unsigned short* kb = (unsigned short*)(ws + 41943040);      // 16.78 MB
  unsigned short* vtb = (unsigned short*)(ws + 58720256);     // 16.78 MB [n,h,dk,t]
  unsigned short* attn_bf = (unsigned short*)(ws + 0);        // alias x_bf
  int* lens = (int*)(ws + 92274688);                          // 32 B

  cvt_all<<<(XQ + WIQ + WOQ + 255) / 256, 256, 0, stream>>>(x, w_in, w_o, x_bf, win_bf, wo_bf,
                                                            kpm, lens);
  // QKV projection: 256x128 blocks, 128x64 wave tiles
  gemm_qkv_wide<<<dim3(32, 24), 256, 0, stream>>>(x_bf, win_bf, b_in, qb, kb, vtb);
  // fused attention (paired q-streams, swapped QK^T, exp2 no-max softmax)
  attn_kernel<<<NB * NHEADS * 8, 256, 0, stream>>>(qb, kb, vtb, lens, attn_bf);
  // output projection: [8192,1024] x [1024,1024]^T -> f32 out
  gemm_out_kernel<<<dim3(64, 8), 256, 0, stream>>>(attn_bf, wo_bf, b_o, out, T_SEQ * NB, DMODEL,
                                                   DMODEL);
}